// Round 4
// baseline (352.247 us; speedup 1.0000x reference)
//
#include <hip/hip_runtime.h>
#include <hip/hip_bf16.h>
#include <stdint.h>

#define LQ 1024
#define BQ 2
#define AQ 14
#define KQ 30
#define EFQ 128
#define EDGE_IN 3152
#define KPAD 3200
#define NCHUNK 50
#define ROWS (BQ*LQ*KQ)            /* 61440 */
#define EIDX_OFF (ROWS*EFQ)        /* 7864320 */

typedef __attribute__((ext_vector_type(8))) short short8;
typedef __attribute__((ext_vector_type(4))) float floatx4;
using bf16_t = __hip_bfloat16;

static __device__ __forceinline__ unsigned short f2bf(float f) {
    __hip_bfloat16 h = __float2bfloat16(f);
    return *reinterpret_cast<unsigned short*>(&h);
}

// ---------------------------------------------------------------------------
// Kernel A: per-(b,i) row — CA distances in FP64 (matches float64 numpy ref
// ordering bit-for-bit), D_adjust, exact top-K selection (min-dist, tie ->
// lower index). One block of 256 threads per row.
// ---------------------------------------------------------------------------
__global__ __launch_bounds__(256) void topk_kernel(
    const float* __restrict__ X, const float* __restrict__ mask,
    float* __restrict__ out, int* __restrict__ idx_ws)
{
    __shared__ double xs[LQ], ys[LQ], zs[LQ], ms[LQ], dist[LQ];
    __shared__ unsigned long long wk[4];
    __shared__ int wi[4];
    __shared__ double dmax_sh[4];

    const int t = threadIdx.x;
    const int b = blockIdx.x >> 10;
    const int i = blockIdx.x & (LQ - 1);

    for (int j = t; j < LQ; j += 256) {
        size_t base = ((size_t)(b*LQ + j))*(AQ*3) + 3;   // atom 1 (CA)
        xs[j] = (double)X[base+0];
        ys[j] = (double)X[base+1];
        zs[j] = (double)X[base+2];
        ms[j] = (double)mask[b*LQ + j];
    }
    __syncthreads();
    const double cx = xs[i], cy = ys[i], cz = zs[i], mi = ms[i];
    double lmax = 0.0;
    for (int j = t; j < LQ; j += 256) {
        double dx = __dsub_rn(cx, xs[j]);
        double dy = __dsub_rn(cy, ys[j]);
        double dz = __dsub_rn(cz, zs[j]);
        double ssq = __dadd_rn(__dadd_rn(__dmul_rn(dx,dx), __dmul_rn(dy,dy)),
                               __dmul_rn(dz,dz));
        double D = __dmul_rn(__dmul_rn(mi, ms[j]), sqrt(__dadd_rn(ssq, 1e-6)));
        dist[j] = D;
        lmax = fmax(lmax, D);
    }
    #pragma unroll
    for (int off = 32; off; off >>= 1) lmax = fmax(lmax, __shfl_xor(lmax, off));
    if ((t & 63) == 0) dmax_sh[t >> 6] = lmax;
    __syncthreads();
    const double dmax = fmax(fmax(dmax_sh[0], dmax_sh[1]),
                             fmax(dmax_sh[2], dmax_sh[3]));
    for (int j = t; j < LQ; j += 256) {
        double m2 = __dmul_rn(mi, ms[j]);
        dist[j] = __dadd_rn(dist[j],
                  __dmul_rn(__dmul_rn(2.0, __dsub_rn(1.0, m2)), dmax));
    }
    __syncthreads();

    for (int k = 0; k < KQ; ++k) {
        unsigned long long bk = ~0ull; int bi = 0x7fffffff;
        for (int j = t; j < LQ; j += 256) {
            // positive doubles: bit pattern is monotone in value
            unsigned long long key = (unsigned long long)__double_as_longlong(dist[j]);
            if (key < bk || (key == bk && j < bi)) { bk = key; bi = j; }
        }
        #pragma unroll
        for (int off = 32; off; off >>= 1) {
            unsigned long long ok = __shfl_xor(bk, off);
            int oi = __shfl_xor(bi, off);
            if (ok < bk || (ok == bk && oi < bi)) { bk = ok; bi = oi; }
        }
        if ((t & 63) == 0) { wk[t >> 6] = bk; wi[t >> 6] = bi; }
        __syncthreads();
        if (t == 0) {
            #pragma unroll
            for (int u = 1; u < 4; ++u)
                if (wk[u] < bk || (wk[u] == bk && wi[u] < bi)) { bk = wk[u]; bi = wi[u]; }
            dist[bi] = __longlong_as_double(0x7ff0000000000000ll);  // +inf: remove
            int rg = (b*LQ + i)*KQ + k;
            idx_ws[rg] = bi;
            out[EIDX_OFF + rg] = (float)bi;             // fp32 output
        }
        __syncthreads();
    }
}

// ---------------------------------------------------------------------------
// Kernel C: pad W (128 x 3152 fp32) into ws as bf16 (128 x 3200), zero pad.
// ---------------------------------------------------------------------------
__global__ __launch_bounds__(256) void wpad_kernel(
    const float* __restrict__ W, bf16_t* __restrict__ wpad)
{
    int idx = blockIdx.x*256 + threadIdx.x;
    if (idx >= EFQ*KPAD) return;
    int n = idx / KPAD, f = idx - n*KPAD;
    float v = (f < EDGE_IN) ? W[(size_t)n*EDGE_IN + f] : 0.0f;
    wpad[idx] = __float2bfloat16(v);
}

// ---------------------------------------------------------------------------
// Kernel B: fused feature-gen + bf16 MFMA GEMM + LayerNorm (fp32 out).
// 64-row M-tile per block (256 threads / 4 waves), N=128, BK=64 (50 chunks).
// ---------------------------------------------------------------------------
struct FusedSmem {
    alignas(16) float atoms[128*45];          // 0..63 center rows, 64..127 neighbor
    alignas(16) unsigned short Alds[64*72];   // features [row][k], stride 72
    alignas(16) unsigned short Blds[128*72];  // W [n][k], stride 72
    alignas(16) float drow[64];
    int residg[128];
    unsigned int maskb[128];
    float gsh[EFQ], bsh[EFQ];
};

__global__ __launch_bounds__(256) void fused_kernel(
    const float* __restrict__ X, const float* __restrict__ atom_mask,
    const bf16_t* __restrict__ wpad, const float* __restrict__ gamma,
    const float* __restrict__ beta, const int* __restrict__ idx_ws,
    float* __restrict__ out)
{
    __shared__ FusedSmem sm;
    const int t = threadIdx.x;
    const int row0 = blockIdx.x * 64;
    const int b = row0 / (LQ*KQ);            // tiles never straddle b (30720 % 64 == 0)

    if (t < 64) {
        int rg = row0 + t;
        int rem = rg - b*(LQ*KQ);
        int i = rem / KQ;
        int j = idx_ws[rg];
        sm.residg[t]    = b*LQ + i;
        sm.residg[64+t] = b*LQ + j;
        sm.drow[t] = (float)j - (float)i;
    }
    if (t < EFQ) { sm.gsh[t] = gamma[t]; sm.bsh[t] = beta[t]; }
    __syncthreads();

    for (int u = t; u < 128*42; u += 256) {  // 21 exact iterations
        int s = u / 42; int e = u - s*42;
        sm.atoms[s*45 + e] = X[(size_t)sm.residg[s]*42 + e];
    }
    __syncthreads();

    if (t < 128) {
        float* at = &sm.atoms[t*45];
        float Nx=at[0],Ny=at[1],Nz=at[2], Cax=at[3],Cay=at[4],Caz=at[5],
              Cx=at[6],Cy=at[7],Cz=at[8];
        float bx=Cax-Nx, by=Cay-Ny, bz=Caz-Nz;
        float ex=Cx-Cax, ey=Cy-Cay, ez=Cz-Caz;
        float ax = by*ez - bz*ey, ay = bz*ex - bx*ez, az = bx*ey - by*ex;
        at[12] = -0.58273431f*ax + 0.56802827f*bx - 0.54067466f*ex + Cax;  // Cb
        at[13] = -0.58273431f*ay + 0.56802827f*by - 0.54067466f*ey + Cay;
        at[14] = -0.58273431f*az + 0.56802827f*bz - 0.54067466f*ez + Caz;
        unsigned mb = 0;
        const float* amp = &atom_mask[(size_t)sm.residg[t]*AQ];
        #pragma unroll
        for (int a = 0; a < AQ; ++a) if (amp[a] > 0.5f) mb |= (1u << a);
        sm.maskb[t] = mb;
    }
    __syncthreads();

    floatx4 acc[8];
    #pragma unroll
    for (int nt = 0; nt < 8; ++nt) acc[nt] = (floatx4){0.f,0.f,0.f,0.f};
    const int w = t >> 6, lane = t & 63, q = lane >> 4, l15 = lane & 15;
    const int rA = t & 63, qq = t >> 6;      // feature-gen map
    const int nB = t >> 1, hB = t & 1;       // B-staging map

    for (int c = 0; c < NCHUNK; ++c) {
        __syncthreads();
        {   // stage W chunk: 32 bf16 per thread, 4x uint4
            const uint4* src = reinterpret_cast<const uint4*>(
                &wpad[(size_t)nB*KPAD + c*64 + hB*32]);
            uint4* dst = reinterpret_cast<uint4*>(&sm.Blds[nB*72 + hB*32]);
            dst[0]=src[0]; dst[1]=src[1]; dst[2]=src[2]; dst[3]=src[3];
        }
        {   // generate 16 features for row rA, group qq
            int f0 = c*64 + qq*16;
            __attribute__((aligned(16))) unsigned short vals[16];
            if (f0 == 0) {
                float d = sm.drow[rA];
                const float fr[8] = {1.0f, 0.31622776601683794f, 0.1f,
                    0.031622776601683794f, 0.01f, 0.0031622776601683794f,
                    0.001f, 0.00031622776601683794f};
                #pragma unroll
                for (int m = 0; m < 8; ++m) {
                    float ang = d * fr[m];
                    vals[m]   = f2bf(cosf(ang));
                    vals[m+8] = f2bf(sinf(ang));
                }
            } else {
                int p = (f0 - 16) >> 4;
                if (p >= AQ*AQ) {
                    #pragma unroll
                    for (int m = 0; m < 16; ++m) vals[m] = 0;
                } else {
                    int a  = (p * 74899) >> 20;      // p / 14 for p < 2048
                    int bp = p - a*14;
                    float combof = ((((sm.maskb[rA] >> a) & 1u) |
                                     ((sm.maskb[64+rA] >> bp) & 1u)) == 0u) ? 1.0f : 0.0f;
                    const float* ca = &sm.atoms[rA*45 + a*3];
                    const float* na = &sm.atoms[(64+rA)*45 + bp*3];
                    float dx = ca[0]-na[0], dy = ca[1]-na[1], dz = ca[2]-na[2];
                    float dab = sqrtf(dx*dx + dy*dy + dz*dz + 1e-6f);
                    #pragma unroll
                    for (int rr = 0; rr < 16; ++rr) {
                        float tt = (dab - (float)rr * 1.3333334f) * 0.8f;
                        vals[rr] = f2bf(__expf(-(tt*tt)) * combof);
                    }
                }
            }
            uint4* dst = reinterpret_cast<uint4*>(&sm.Alds[rA*72 + qq*16]);
            dst[0] = *reinterpret_cast<uint4*>(&vals[0]);
            dst[1] = *reinterpret_cast<uint4*>(&vals[8]);
        }
        __syncthreads();
        #pragma unroll
        for (int ks = 0; ks < 2; ++ks) {
            short8 afrag = *reinterpret_cast<short8*>(
                &sm.Alds[(w*16 + l15)*72 + ks*32 + q*8]);
            #pragma unroll
            for (int nt = 0; nt < 8; ++nt) {
                short8 bfrag = *reinterpret_cast<short8*>(
                    &sm.Blds[(nt*16 + l15)*72 + ks*32 + q*8]);
                acc[nt] = __builtin_amdgcn_mfma_f32_16x16x32_bf16(afrag, bfrag, acc[nt], 0, 0, 0);
            }
        }
    }

    // LayerNorm epilogue. C/D layout: col = lane&15, row = quad*4 + reg.
    #pragma unroll
    for (int v = 0; v < 4; ++v) {
        float s = 0.f, s2 = 0.f;
        #pragma unroll
        for (int nt = 0; nt < 8; ++nt) { float x = acc[nt][v]; s += x; s2 += x*x; }
        #pragma unroll
        for (int off = 1; off < 16; off <<= 1) {
            s  += __shfl_xor(s,  off);
            s2 += __shfl_xor(s2, off);
        }
        float mean = s * (1.0f/128.0f);
        float var  = s2 * (1.0f/128.0f) - mean*mean;
        float rstd = 1.0f / sqrtf(var + 1e-5f);
        int row_l = w*16 + q*4 + v;
        size_t obase = (size_t)(row0 + row_l)*EFQ;
        #pragma unroll
        for (int nt = 0; nt < 8; ++nt) {
            int col = nt*16 + l15;
            out[obase + col] = (acc[nt][v] - mean)*rstd*sm.gsh[col] + sm.bsh[col];
        }
    }
}

extern "C" void kernel_launch(void* const* d_in, const int* in_sizes, int n_in,
                              void* d_out, int out_size, void* d_ws, size_t ws_size,
                              hipStream_t stream)
{
    const float* X         = (const float*)d_in[0];
    const float* mask      = (const float*)d_in[1];
    // d_in[2] residue_idx, d_in[3] chain_labels: unused by the reference math
    const float* atom_mask = (const float*)d_in[4];
    const float* W         = (const float*)d_in[5];
    const float* gamma     = (const float*)d_in[6];
    const float* beta      = (const float*)d_in[7];
    float* out = (float*)d_out;

    int*    idx_ws = (int*)d_ws;                                  // 61440*4 B
    bf16_t* wpad   = (bf16_t*)((char*)d_ws + 262144);             // 128*3200*2 B

    hipLaunchKernelGGL(wpad_kernel, dim3((EFQ*KPAD + 255)/256), dim3(256), 0, stream,
                       W, wpad);
    hipLaunchKernelGGL(topk_kernel, dim3(BQ*LQ), dim3(256), 0, stream,
                       X, mask, out, idx_ws);
    hipLaunchKernelGGL(fused_kernel, dim3(ROWS/64), dim3(256), 0, stream,
                       X, atom_mask, wpad, gamma, beta, idx_ws, out);
}

// Round 5
// 264.066 us; speedup vs baseline: 1.3339x; 1.3339x over previous
//
#include <hip/hip_runtime.h>
#include <hip/hip_bf16.h>
#include <stdint.h>

#define LQ 1024
#define BQ 2
#define AQ 14
#define KQ 30
#define EFQ 128
#define EDGE_IN 3152
#define KPAD 3200
#define NCHUNK 50
#define ROWS (BQ*LQ*KQ)            /* 61440 */
#define EIDX_OFF (ROWS*EFQ)        /* 7864320 */

typedef __attribute__((ext_vector_type(8))) short short8;
typedef __attribute__((ext_vector_type(4))) float floatx4;
using bf16_t = __hip_bfloat16;
typedef unsigned long long ull;

static __device__ __forceinline__ unsigned short f2bf(float f) {
    __hip_bfloat16 h = __float2bfloat16(f);
    return *reinterpret_cast<unsigned short*>(&h);
}

// ---------------------------------------------------------------------------
// Kernel A v2: one wave per (b,i) row, zero barriers. 16 fp64 candidates per
// lane in registers; 30 rounds of (masked local min + 64-lane butterfly).
// fp64 math matches the float64 numpy reference ordering bit-for-bit;
// (key, idx) lexicographic compare = lower-index tie-break.
// ---------------------------------------------------------------------------
__global__ __launch_bounds__(256) void topk_kernel(
    const float* __restrict__ X, const float* __restrict__ mask,
    float* __restrict__ out, int* __restrict__ idx_ws)
{
    const int lane = threadIdx.x & 63;
    const int row  = blockIdx.x*4 + (threadIdx.x >> 6);   // 0..2047
    const int b = row >> 10, i = row & (LQ - 1);

    size_t cb = ((size_t)(b*LQ + i))*42 + 3;              // CA of center
    const double cx = (double)X[cb], cy = (double)X[cb+1], cz = (double)X[cb+2];
    const double mi = (double)mask[b*LQ + i];

    double D[16], m2[16];
    double lmax = 0.0;
    #pragma unroll
    for (int s = 0; s < 16; ++s) {
        int j = s*64 + lane;
        size_t base = ((size_t)(b*LQ + j))*42 + 3;
        double dx = __dsub_rn(cx, (double)X[base+0]);
        double dy = __dsub_rn(cy, (double)X[base+1]);
        double dz = __dsub_rn(cz, (double)X[base+2]);
        double ssq = __dadd_rn(__dadd_rn(__dmul_rn(dx,dx), __dmul_rn(dy,dy)),
                               __dmul_rn(dz,dz));
        double mm = __dmul_rn(mi, (double)mask[b*LQ + j]);
        double Dv = __dmul_rn(mm, sqrt(__dadd_rn(ssq, 1e-6)));
        D[s] = Dv; m2[s] = mm;
        lmax = fmax(lmax, Dv);
    }
    #pragma unroll
    for (int off = 32; off; off >>= 1) lmax = fmax(lmax, __shfl_xor(lmax, off));

    ull keys[16];
    #pragma unroll
    for (int s = 0; s < 16; ++s) {
        double adj = __dmul_rn(__dmul_rn(2.0, __dsub_rn(1.0, m2[s])), lmax);
        keys[s] = (ull)__double_as_longlong(__dadd_rn(D[s], adj));
    }

    unsigned cons = 0;
    for (int k = 0; k < KQ; ++k) {
        ull bk = ~0ull; int bi = 1 << 30;
        #pragma unroll
        for (int s = 0; s < 16; ++s) {
            int j = s*64 + lane;
            bool alive = !((cons >> s) & 1u);
            if (alive && (keys[s] < bk || (keys[s] == bk && j < bi))) {
                bk = keys[s]; bi = j;
            }
        }
        #pragma unroll
        for (int off = 32; off; off >>= 1) {
            ull okk = __shfl_xor(bk, off);
            int oii = __shfl_xor(bi, off);
            if (okk < bk || (okk == bk && oii < bi)) { bk = okk; bi = oii; }
        }
        if ((bi & 63) == lane) cons |= (1u << (bi >> 6));
        if (lane == 0) {
            int rg = row*KQ + k;
            idx_ws[rg] = bi;
            out[EIDX_OFF + rg] = (float)bi;
        }
    }
}

// ---------------------------------------------------------------------------
// Kernel C: pad W (128 x 3152 fp32) into ws as bf16 (128 x 3200), zero pad.
// ---------------------------------------------------------------------------
__global__ __launch_bounds__(256) void wpad_kernel(
    const float* __restrict__ W, bf16_t* __restrict__ wpad)
{
    int idx = blockIdx.x*256 + threadIdx.x;
    if (idx >= EFQ*KPAD) return;
    int n = idx / KPAD, f = idx - n*KPAD;
    float v = (f < EDGE_IN) ? W[(size_t)n*EDGE_IN + f] : 0.0f;
    wpad[idx] = __float2bfloat16(v);
}

// ---------------------------------------------------------------------------
// Kernel B v2: fused feature-gen (A-frags in registers) + bf16 MFMA GEMM with
// async double-buffered B staging (global_load_lds, XOR-swizzled) + LayerNorm.
// One barrier per K-chunk.
// ---------------------------------------------------------------------------
struct FusedSmem {
    alignas(16) float atoms[128*45];           // 0..63 center rows, 64..127 neighbor
    alignas(16) unsigned short Bl[2][128*64];  // W chunk, row n stride 64, XOR-swizzled
    alignas(16) float drow[64];
    int residg[128];
    unsigned int maskb[128];
    float gsh[EFQ], bsh[EFQ];
};

// Generate 8 contiguous features [f0, f0+8) for tile-local row m.
static __device__ __forceinline__ void gen8(
    const FusedSmem& sm, int m, int f0, unsigned short* __restrict__ v)
{
    if (f0 >= 16) {
        int p = (f0 - 16) >> 4;
        if (p >= AQ*AQ) {
            #pragma unroll
            for (int j = 0; j < 8; ++j) v[j] = 0;
            return;
        }
        int rbase = (f0 - 16) & 15;                 // 0 or 8
        int a  = (p * 74899) >> 20;                 // p / 14 for p < 2048
        int bp = p - a*14;
        float combof = ((((sm.maskb[m] >> a) & 1u) |
                         ((sm.maskb[64+m] >> bp) & 1u)) == 0u) ? 1.0f : 0.0f;
        const float* ca = &sm.atoms[m*45 + a*3];
        const float* na = &sm.atoms[(64+m)*45 + bp*3];
        float dx = ca[0]-na[0], dy = ca[1]-na[1], dz = ca[2]-na[2];
        float dab = sqrtf(dx*dx + dy*dy + dz*dz + 1e-6f);
        #pragma unroll
        for (int j = 0; j < 8; ++j) {
            float tt = (dab - (float)(rbase + j) * 1.3333334f) * 0.8f;
            v[j] = f2bf(__expf(-(tt*tt)) * combof);
        }
    } else {
        float d = sm.drow[m];
        const float fr[8] = {1.0f, 0.31622776601683794f, 0.1f,
            0.031622776601683794f, 0.01f, 0.0031622776601683794f,
            0.001f, 0.00031622776601683794f};
        if (f0 == 0) {
            #pragma unroll
            for (int j = 0; j < 8; ++j) v[j] = f2bf(cosf(d * fr[j]));
        } else {
            #pragma unroll
            for (int j = 0; j < 8; ++j) v[j] = f2bf(sinf(d * fr[j]));
        }
    }
}

__global__ __launch_bounds__(256) void fused_kernel(
    const float* __restrict__ X, const float* __restrict__ atom_mask,
    const bf16_t* __restrict__ wpad, const float* __restrict__ gamma,
    const float* __restrict__ beta, const int* __restrict__ idx_ws,
    float* __restrict__ out)
{
    __shared__ FusedSmem sm;
    const int t = threadIdx.x;
    const int row0 = blockIdx.x * 64;
    const int b = row0 / (LQ*KQ);            // tiles never straddle b (30720 % 64 == 0)

    if (t < 64) {
        int rg = row0 + t;
        int rem = rg - b*(LQ*KQ);
        int i = rem / KQ;
        int j = idx_ws[rg];
        sm.residg[t]    = b*LQ + i;
        sm.residg[64+t] = b*LQ + j;
        sm.drow[t] = (float)j - (float)i;
    }
    if (t < EFQ) { sm.gsh[t] = gamma[t]; sm.bsh[t] = beta[t]; }
    __syncthreads();

    for (int u = t; u < 128*42; u += 256) {  // 21 exact iterations
        int s = u / 42; int e = u - s*42;
        sm.atoms[s*45 + e] = X[(size_t)sm.residg[s]*42 + e];
    }
    __syncthreads();

    if (t < 128) {
        float* at = &sm.atoms[t*45];
        float Nx=at[0],Ny=at[1],Nz=at[2], Cax=at[3],Cay=at[4],Caz=at[5],
              Cx=at[6],Cy=at[7],Cz=at[8];
        float bx=Cax-Nx, by=Cay-Ny, bz=Caz-Nz;
        float ex=Cx-Cax, ey=Cy-Cay, ez=Cz-Caz;
        float ax = by*ez - bz*ey, ay = bz*ex - bx*ez, az = bx*ey - by*ex;
        at[12] = -0.58273431f*ax + 0.56802827f*bx - 0.54067466f*ex + Cax;  // Cb
        at[13] = -0.58273431f*ay + 0.56802827f*by - 0.54067466f*ey + Cay;
        at[14] = -0.58273431f*az + 0.56802827f*bz - 0.54067466f*ez + Caz;
        unsigned mb = 0;
        const float* amp = &atom_mask[(size_t)sm.residg[t]*AQ];
        #pragma unroll
        for (int a = 0; a < AQ; ++a) if (amp[a] > 0.5f) mb |= (1u << a);
        sm.maskb[t] = mb;
    }

    const int w = t >> 6, lane = t & 63, q = lane >> 4, l15 = lane & 15;
    const int m = w*16 + l15;                 // tile-local row this thread's A-frag covers

    // Async B staging: lane-contiguous LDS (global_load_lds constraint), with
    // XOR swizzle on the SOURCE k-block so ds_read banks stay 2-way (free):
    // LDS slot (n, s) holds k-block s ^ (n&7).
    auto stage = [&](int c, int buf) {
        #pragma unroll
        for (int i2 = 0; i2 < 4; ++i2) {
            int region = w*4 + i2;                        // 8 rows per region
            int n = region*8 + (lane >> 3);
            int kbsrc = (lane & 7) ^ (lane >> 3);         // (slot) ^ (n&7)
            const bf16_t* g = wpad + (size_t)n*KPAD + c*64 + kbsrc*8;
            __builtin_amdgcn_global_load_lds(
                (const __attribute__((address_space(1))) uint32_t*)g,
                (__attribute__((address_space(3))) uint32_t*)&sm.Bl[buf][region*512],
                16, 0, 0);
        }
    };

    floatx4 acc[8];
    #pragma unroll
    for (int nt = 0; nt < 8; ++nt) acc[nt] = (floatx4){0.f,0.f,0.f,0.f};

    stage(0, 0);                              // needs residg? no — only wpad. safe pre-barrier
    __syncthreads();                          // atoms/maskb ready for feature-gen

    for (int c = 0; c < NCHUNK; ++c) {
        const int cur = c & 1;
        // A-fragments for this thread: features [c*64+q*8, +8) and +32, row m
        __attribute__((aligned(16))) unsigned short va[16];
        gen8(sm, m, c*64 + q*8,      &va[0]);
        gen8(sm, m, c*64 + 32 + q*8, &va[8]);
        __syncthreads();                      // drains vmcnt: Bl[cur] ready; prior reads done
        if (c + 1 < NCHUNK) stage(c + 1, cur ^ 1);
        short8 a0 = *reinterpret_cast<short8*>(&va[0]);
        short8 a1 = *reinterpret_cast<short8*>(&va[8]);
        #pragma unroll
        for (int nt = 0; nt < 8; ++nt) {
            int n = nt*16 + l15;
            short8 b0 = *reinterpret_cast<const short8*>(
                &sm.Bl[cur][n*64 + ((q ^ (n&7))*8)]);
            short8 b1 = *reinterpret_cast<const short8*>(
                &sm.Bl[cur][n*64 + (((4+q) ^ (n&7))*8)]);
            acc[nt] = __builtin_amdgcn_mfma_f32_16x16x32_bf16(a0, b0, acc[nt], 0, 0, 0);
            acc[nt] = __builtin_amdgcn_mfma_f32_16x16x32_bf16(a1, b1, acc[nt], 0, 0, 0);
        }
    }

    // LayerNorm epilogue. C/D layout: col = lane&15, row = quad*4 + reg.
    #pragma unroll
    for (int v = 0; v < 4; ++v) {
        float s = 0.f, s2 = 0.f;
        #pragma unroll
        for (int nt = 0; nt < 8; ++nt) { float x = acc[nt][v]; s += x; s2 += x*x; }
        #pragma unroll
        for (int off = 1; off < 16; off <<= 1) {
            s  += __shfl_xor(s,  off);
            s2 += __shfl_xor(s2, off);
        }
        float mean = s * (1.0f/128.0f);
        float var  = s2 * (1.0f/128.0f) - mean*mean;
        float rstd = 1.0f / sqrtf(var + 1e-5f);
        int row_l = w*16 + q*4 + v;
        size_t obase = (size_t)(row0 + row_l)*EFQ;
        #pragma unroll
        for (int nt = 0; nt < 8; ++nt) {
            int col = nt*16 + l15;
            out[obase + col] = (acc[nt][v] - mean)*rstd*sm.gsh[col] + sm.bsh[col];
        }
    }
}

extern "C" void kernel_launch(void* const* d_in, const int* in_sizes, int n_in,
                              void* d_out, int out_size, void* d_ws, size_t ws_size,
                              hipStream_t stream)
{
    const float* X         = (const float*)d_in[0];
    const float* mask      = (const float*)d_in[1];
    // d_in[2] residue_idx, d_in[3] chain_labels: unused by the reference math
    const float* atom_mask = (const float*)d_in[4];
    const float* W         = (const float*)d_in[5];
    const float* gamma     = (const float*)d_in[6];
    const float* beta      = (const float*)d_in[7];
    float* out = (float*)d_out;

    int*    idx_ws = (int*)d_ws;                                  // 61440*4 B
    bf16_t* wpad   = (bf16_t*)((char*)d_ws + 262144);             // 128*3200*2 B

    hipLaunchKernelGGL(wpad_kernel, dim3((EFQ*KPAD + 255)/256), dim3(256), 0, stream,
                       W, wpad);
    hipLaunchKernelGGL(topk_kernel, dim3(BQ*LQ/4), dim3(256), 0, stream,
                       X, mask, out, idx_ws);
    hipLaunchKernelGGL(fused_kernel, dim3(ROWS/64), dim3(256), 0, stream,
                       X, atom_mask, wpad, gamma, beta, idx_ws, out);
}

// Round 6
// 204.466 us; speedup vs baseline: 1.7228x; 1.2915x over previous
//
#include <hip/hip_runtime.h>
#include <hip/hip_bf16.h>
#include <stdint.h>

#define LQ 1024
#define BQ 2
#define AQ 14
#define KQ 30
#define EFQ 128
#define EDGE_IN 3152
#define KPAD 3200
#define NCHUNK 50
#define ROWS (BQ*LQ*KQ)            /* 61440 */
#define EIDX_OFF (ROWS*EFQ)        /* 7864320 */

typedef __attribute__((ext_vector_type(8))) short short8;
typedef __attribute__((ext_vector_type(4))) float floatx4;
using bf16_t = __hip_bfloat16;
typedef unsigned long long ull;

static __device__ __forceinline__ unsigned short f2bf(float f) {
    __hip_bfloat16 h = __float2bfloat16(f);
    return *reinterpret_cast<unsigned short*>(&h);
}

// ---------------------------------------------------------------------------
// Kernel A v3: one wave per (b,i) row, zero barriers, lean registers.
// Fast path (all mask==1, wave-uniform check): ordering by fp64 ssq ==
// ordering by m2*sqrt(ssq+1e-6)+adj (monotone) -> no sqrt, no lmax pass.
// Slow path: exact fp64 replication of the reference. (key,idx) lexicographic
// selection = ascending D, lower-index tie-break, matching lax.top_k.
// ---------------------------------------------------------------------------
__global__ __launch_bounds__(256) void topk_kernel(
    const float* __restrict__ X, const float* __restrict__ mask,
    float* __restrict__ out, int* __restrict__ idx_ws)
{
    const int lane = threadIdx.x & 63;
    const int row  = blockIdx.x*4 + (threadIdx.x >> 6);   // 0..2047
    const int b = row >> 10, i = row & (LQ - 1);

    size_t cb = ((size_t)(b*LQ + i))*42 + 3;              // CA of center
    const float cxf = X[cb], cyf = X[cb+1], czf = X[cb+2];
    const float mif = mask[b*LQ + i];
    const double cx = (double)cxf, cy = (double)cyf, cz = (double)czf;

    double Dk[16];      // ssq, then overlaid with final sort keys
    float  mf[16];
    bool allone = (mif == 1.0f);
    #pragma unroll
    for (int s = 0; s < 16; ++s) {
        int j = s*64 + lane;
        size_t base = ((size_t)(b*LQ + j))*42 + 3;
        float xj = X[base+0], yj = X[base+1], zj = X[base+2];
        mf[s] = mask[b*LQ + j];
        double dx = __dsub_rn(cx, (double)xj);
        double dy = __dsub_rn(cy, (double)yj);
        double dz = __dsub_rn(cz, (double)zj);
        Dk[s] = __dadd_rn(__dadd_rn(__dmul_rn(dx,dx), __dmul_rn(dy,dy)),
                          __dmul_rn(dz,dz));
        allone = allone && (mf[s] == 1.0f);
    }

    if (!__all(allone ? 1 : 0)) {
        // exact general path: D = mi*mj*sqrt(ssq+1e-6); adj = 2(1-m2)*max(D)
        const double mi_d = (double)mif;
        double lmax = 0.0;
        #pragma unroll
        for (int s = 0; s < 16; ++s) {
            double m2 = __dmul_rn(mi_d, (double)mf[s]);
            Dk[s] = __dmul_rn(m2, sqrt(__dadd_rn(Dk[s], 1e-6)));
            lmax = fmax(lmax, Dk[s]);
        }
        #pragma unroll
        for (int off = 32; off; off >>= 1) lmax = fmax(lmax, __shfl_xor(lmax, off));
        #pragma unroll
        for (int s = 0; s < 16; ++s) {
            double m2 = __dmul_rn(mi_d, (double)mf[s]);
            Dk[s] = __dadd_rn(Dk[s],
                    __dmul_rn(__dmul_rn(2.0, __dsub_rn(1.0, m2)), lmax));
        }
    }
    // else: keys = ssq (positive doubles; bit pattern monotone in value)

    unsigned cons = 0;
    for (int k = 0; k < KQ; ++k) {
        ull bk = ~0ull; int bi = 1 << 30;
        #pragma unroll
        for (int s = 0; s < 16; ++s) {
            ull key = (ull)__double_as_longlong(Dk[s]);
            bool alive = !((cons >> s) & 1u);
            if (alive && key < bk) { bk = key; bi = s*64 + lane; }  // strict <: lowest s wins ties (lowest j)
        }
        #pragma unroll
        for (int off = 32; off; off >>= 1) {
            ull okk = __shfl_xor(bk, off);
            int oii = __shfl_xor(bi, off);
            if (okk < bk || (okk == bk && oii < bi)) { bk = okk; bi = oii; }
        }
        if ((bi & 63) == lane) cons |= (1u << (bi >> 6));
        if (lane == 0) {
            int rg = row*KQ + k;
            idx_ws[rg] = bi;
            out[EIDX_OFF + rg] = (float)bi;
        }
    }
}

// ---------------------------------------------------------------------------
// Kernel C: pad W (128 x 3152 fp32) into ws as bf16 (128 x 3200), zero pad.
// ---------------------------------------------------------------------------
__global__ __launch_bounds__(256) void wpad_kernel(
    const float* __restrict__ W, bf16_t* __restrict__ wpad)
{
    int idx = blockIdx.x*256 + threadIdx.x;
    if (idx >= EFQ*KPAD) return;
    int n = idx / KPAD, f = idx - n*KPAD;
    float v = (f < EDGE_IN) ? W[(size_t)n*EDGE_IN + f] : 0.0f;
    wpad[idx] = __float2bfloat16(v);
}

// ---------------------------------------------------------------------------
// Kernel B v3: fused feature-gen (A-frags in registers) + bf16 MFMA GEMM,
// single-buffer async B staging (global_load_lds, XOR-swizzled) + LayerNorm.
// LDS ~40 KB -> 4 blocks/CU (16 waves/CU) for latency hiding; the staging
// drain is covered by feature-gen VALU between stage() and the barrier.
// ---------------------------------------------------------------------------
struct FusedSmem {
    alignas(16) float atoms[128*42];           // 0..63 center rows, 64..127 neighbor (21504 B)
    alignas(16) unsigned short Bl[128*64];     // W chunk, row n stride 64, XOR-swizzled (16384 B)
    alignas(16) float drow[64];
    int residg[128];
    unsigned int maskb[128];
    float gsh[EFQ], bsh[EFQ];
};                                             // total ~40.2 KB

// Generate 8 contiguous features [f0, f0+8) for tile-local row m.
// RBF: exp(-((d - r*4/3)*0.8)^2) = exp2(-(u - r*v)^2), u=d*0.96089846, v=1.28119795
static __device__ __forceinline__ void gen8(
    const FusedSmem& sm, int m, int f0, unsigned short* __restrict__ v)
{
    if (f0 >= 16) {
        int p = (f0 - 16) >> 4;
        if (p >= AQ*AQ) {
            #pragma unroll
            for (int j = 0; j < 8; ++j) v[j] = 0;
            return;
        }
        int rbase = (f0 - 16) & 15;                 // 0 or 8
        int a  = (p * 74899) >> 20;                 // p / 14 for p < 2048
        int bp = p - a*14;
        float combof = ((((sm.maskb[m] >> a) & 1u) |
                         ((sm.maskb[64+m] >> bp) & 1u)) == 0u) ? 1.0f : 0.0f;
        const float* ca = &sm.atoms[m*42 + a*3];
        const float* na = &sm.atoms[(64+m)*42 + bp*3];
        float dx = ca[0]-na[0], dy = ca[1]-na[1], dz = ca[2]-na[2];
        float dab = sqrtf(dx*dx + dy*dy + dz*dz + 1e-6f);
        float u = dab * 0.96089846f;                // 0.8*sqrt(log2 e)
        #pragma unroll
        for (int j = 0; j < 8; ++j) {
            float tt = __fmaf_rn(-(float)(rbase + j), 1.28119795f, u);
            float e  = __builtin_amdgcn_exp2f(-(tt*tt));
            v[j] = f2bf(e * combof);
        }
    } else {
        float d = sm.drow[m];
        const float fr[8] = {1.0f, 0.31622776601683794f, 0.1f,
            0.031622776601683794f, 0.01f, 0.0031622776601683794f,
            0.001f, 0.00031622776601683794f};
        if (f0 == 0) {
            #pragma unroll
            for (int j = 0; j < 8; ++j) v[j] = f2bf(__cosf(d * fr[j]));
        } else {
            #pragma unroll
            for (int j = 0; j < 8; ++j) v[j] = f2bf(__sinf(d * fr[j]));
        }
    }
}

__global__ __launch_bounds__(256) void fused_kernel(
    const float* __restrict__ X, const float* __restrict__ atom_mask,
    const bf16_t* __restrict__ wpad, const float* __restrict__ gamma,
    const float* __restrict__ beta, const int* __restrict__ idx_ws,
    float* __restrict__ out)
{
    __shared__ FusedSmem sm;
    const int t = threadIdx.x;
    const int row0 = blockIdx.x * 64;
    const int b = row0 / (LQ*KQ);            // tiles never straddle b (30720 % 64 == 0)

    if (t < 64) {
        int rg = row0 + t;
        int rem = rg - b*(LQ*KQ);
        int i = rem / KQ;
        int j = idx_ws[rg];
        sm.residg[t]    = b*LQ + i;
        sm.residg[64+t] = b*LQ + j;
        sm.drow[t] = (float)j - (float)i;
    }
    if (t < EFQ) { sm.gsh[t] = gamma[t]; sm.bsh[t] = beta[t]; }
    __syncthreads();

    for (int u = t; u < 128*42; u += 256) {  // 21 exact iterations
        int s = u / 42; int e = u - s*42;
        sm.atoms[s*42 + e] = X[(size_t)sm.residg[s]*42 + e];
    }
    __syncthreads();

    if (t < 128) {
        float* at = &sm.atoms[t*42];
        float Nx=at[0],Ny=at[1],Nz=at[2], Cax=at[3],Cay=at[4],Caz=at[5],
              Cx=at[6],Cy=at[7],Cz=at[8];
        float bx=Cax-Nx, by=Cay-Ny, bz=Caz-Nz;
        float ex=Cx-Cax, ey=Cy-Cay, ez=Cz-Caz;
        float ax = by*ez - bz*ey, ay = bz*ex - bx*ez, az = bx*ey - by*ex;
        at[12] = -0.58273431f*ax + 0.56802827f*bx - 0.54067466f*ex + Cax;  // Cb
        at[13] = -0.58273431f*ay + 0.56802827f*by - 0.54067466f*ey + Cay;
        at[14] = -0.58273431f*az + 0.56802827f*bz - 0.54067466f*ez + Caz;
        unsigned mb = 0;
        const float* amp = &atom_mask[(size_t)sm.residg[t]*AQ];
        #pragma unroll
        for (int a = 0; a < AQ; ++a) if (amp[a] > 0.5f) mb |= (1u << a);
        sm.maskb[t] = mb;
    }

    const int w = t >> 6, lane = t & 63, q = lane >> 4, l15 = lane & 15;
    const int m = w*16 + l15;                 // tile-local row this thread's A-frag covers

    // Async B staging: lane-contiguous LDS (global_load_lds constraint), XOR
    // swizzle on the SOURCE k-block: LDS slot (n, s) holds k-block s ^ (n&7).
    auto stage = [&](int c) {
        #pragma unroll
        for (int i2 = 0; i2 < 4; ++i2) {
            int region = w*4 + i2;                        // 8 rows per region
            int n = region*8 + (lane >> 3);
            int kbsrc = (lane & 7) ^ (lane >> 3);         // (slot) ^ (n&7)
            const bf16_t* g = wpad + (size_t)n*KPAD + c*64 + kbsrc*8;
            __builtin_amdgcn_global_load_lds(
                (const __attribute__((address_space(1))) uint32_t*)g,
                (__attribute__((address_space(3))) uint32_t*)&sm.Bl[region*512],
                16, 0, 0);
        }
    };

    floatx4 acc[8];
    #pragma unroll
    for (int nt = 0; nt < 8; ++nt) acc[nt] = (floatx4){0.f,0.f,0.f,0.f};

    __syncthreads();                          // atoms/maskb ready

    for (int c = 0; c < NCHUNK; ++c) {
        if (c) __syncthreads();               // all reads of previous B chunk done
        stage(c);                             // async global->LDS, in flight during gen
        __attribute__((aligned(16))) unsigned short va[16];
        gen8(sm, m, c*64 + q*8,      &va[0]);
        gen8(sm, m, c*64 + 32 + q*8, &va[8]);
        __syncthreads();                      // drains vmcnt: Bl ready
        short8 a0 = *reinterpret_cast<short8*>(&va[0]);
        short8 a1 = *reinterpret_cast<short8*>(&va[8]);
        #pragma unroll
        for (int nt = 0; nt < 8; ++nt) {
            int n = nt*16 + l15;
            short8 b0 = *reinterpret_cast<const short8*>(
                &sm.Bl[n*64 + ((q ^ (n&7))*8)]);
            short8 b1 = *reinterpret_cast<const short8*>(
                &sm.Bl[n*64 + (((4+q) ^ (n&7))*8)]);
            acc[nt] = __builtin_amdgcn_mfma_f32_16x16x32_bf16(a0, b0, acc[nt], 0, 0, 0);
            acc[nt] = __builtin_amdgcn_mfma_f32_16x16x32_bf16(a1, b1, acc[nt], 0, 0, 0);
        }
    }

    // LayerNorm epilogue. C/D layout: col = lane&15, row = quad*4 + reg.
    #pragma unroll
    for (int v = 0; v < 4; ++v) {
        float s = 0.f, s2 = 0.f;
        #pragma unroll
        for (int nt = 0; nt < 8; ++nt) { float x = acc[nt][v]; s += x; s2 += x*x; }
        #pragma unroll
        for (int off = 1; off < 16; off <<= 1) {
            s  += __shfl_xor(s,  off);
            s2 += __shfl_xor(s2, off);
        }
        float mean = s * (1.0f/128.0f);
        float var  = s2 * (1.0f/128.0f) - mean*mean;
        float rstd = 1.0f / sqrtf(var + 1e-5f);
        int row_l = w*16 + q*4 + v;
        size_t obase = (size_t)(row0 + row_l)*EFQ;
        #pragma unroll
        for (int nt = 0; nt < 8; ++nt) {
            int col = nt*16 + l15;
            out[obase + col] = (acc[nt][v] - mean)*rstd*sm.gsh[col] + sm.bsh[col];
        }
    }
}

extern "C" void kernel_launch(void* const* d_in, const int* in_sizes, int n_in,
                              void* d_out, int out_size, void* d_ws, size_t ws_size,
                              hipStream_t stream)
{
    const float* X         = (const float*)d_in[0];
    const float* mask      = (const float*)d_in[1];
    // d_in[2] residue_idx, d_in[3] chain_labels: unused by the reference math
    const float* atom_mask = (const float*)d_in[4];
    const float* W         = (const float*)d_in[5];
    const float* gamma     = (const float*)d_in[6];
    const float* beta      = (const float*)d_in[7];
    float* out = (float*)d_out;

    int*    idx_ws = (int*)d_ws;                                  // 61440*4 B
    bf16_t* wpad   = (bf16_t*)((char*)d_ws + 262144);             // 128*3200*2 B

    hipLaunchKernelGGL(wpad_kernel, dim3((EFQ*KPAD + 255)/256), dim3(256), 0, stream,
                       W, wpad);
    hipLaunchKernelGGL(topk_kernel, dim3(BQ*LQ/4), dim3(256), 0, stream,
                       X, mask, out, idx_ws);
    hipLaunchKernelGGL(fused_kernel, dim3(ROWS/64), dim3(256), 0, stream,
                       X, atom_mask, wpad, gamma, beta, idx_ws, out);
}